// Round 2
// baseline (1215.901 us; speedup 1.0000x reference)
//
#include <hip/hip_runtime.h>
#include <cstdint>
#include <cstddef>

// OVOLinearSemanticExtractor (last_only=1)
// Strategy: replicate the reference's FP32 arithmetic exactly:
//   conv1x1: fp32 fused-FMA chain over c ascending (init 0), then fp32 +bias
//   bilinear: H-axis then W-axis, each t = fma(w1, v1, rnd(w0*v0));
//             edge = single tap with normalized weight exactly 1.0 -> copy
//   total = ((L0+L1)+L2)+L3 ordered fp32 adds; vote on total > 0

#define N_BATCH 8
#define N_OVO   66
#define N_CLS   12

__constant__ unsigned char PAIR_I[N_OVO] = {
  0,0,0,0,0,0,0,0,0,0,0,
  1,1,1,1,1,1,1,1,1,1,
  2,2,2,2,2,2,2,2,2,
  3,3,3,3,3,3,3,3,
  4,4,4,4,4,4,4,
  5,5,5,5,5,5,
  6,6,6,6,6,
  7,7,7,7,
  8,8,8,
  9,9,
  10
};
__constant__ unsigned char PAIR_J[N_OVO] = {
  1,2,3,4,5,6,7,8,9,10,11,
  2,3,4,5,6,7,8,9,10,11,
  3,4,5,6,7,8,9,10,11,
  4,5,6,7,8,9,10,11,
  5,6,7,8,9,10,11,
  6,7,8,9,10,11,
  7,8,9,10,11,
  8,9,10,11,
  9,10,11,
  10,11,
  11
};

// ---------------------------------------------------------------------------
// Conv 1x1 (stages 0-2), fp32, strict c-ascending FMA chain per output.
// Block: 256 threads = 64 pixels x 4 o-groups (17 outputs each).
// ---------------------------------------------------------------------------
template<int C, int S2>
__global__ __launch_bounds__(256)
void conv1x1_f32(const float* __restrict__ x, const float* __restrict__ w,
                 const float* __restrict__ b, float* __restrict__ out)
{
    const int tpx = threadIdx.x & 63;
    const int og  = threadIdx.x >> 6;       // 0..3
    const int o0  = og * 17;                // 0,17,34,51
    const int n   = blockIdx.y;
    const int pxb = blockIdx.x * 64;

    __shared__ float xs[32 * 64];           // [k][pixel]
    __shared__ float ws[32 * 68];           // [k][o], padded

    float acc[17];
#pragma unroll
    for (int oi = 0; oi < 17; ++oi) acc[oi] = 0.0f;

    const int nchunks = C / 32;
    for (int ch = 0; ch < nchunks; ++ch) {
        const int c0 = ch * 32;
        __syncthreads();
#pragma unroll
        for (int r = 0; r < 8; ++r) {
            int idx = threadIdx.x + 256 * r;      // 0..2047
            int k = idx >> 6, p = idx & 63;
            xs[idx] = x[((size_t)n * C + (c0 + k)) * S2 + pxb + p];
        }
        for (int idx = threadIdx.x; idx < 32 * 68; idx += 256) {
            int k = idx / 68, o = idx - k * 68;
            ws[idx] = (o < N_OVO) ? w[(size_t)o * C + c0 + k] : 0.0f;
        }
        __syncthreads();
#pragma unroll 4
        for (int k = 0; k < 32; ++k) {
            float xd = xs[k * 64 + tpx];
#pragma unroll
            for (int oi = 0; oi < 17; ++oi)
                acc[oi] = __fmaf_rn(ws[k * 68 + o0 + oi], xd, acc[oi]);
        }
    }

#pragma unroll
    for (int oi = 0; oi < 17; ++oi) {
        int o = o0 + oi;
        if (o < N_OVO)
            out[((size_t)n * N_OVO + o) * S2 + pxb + tpx] = __fadd_rn(acc[oi], b[o]);
    }
}

// H-then-W bilinear combine, fp32, reference order.
__device__ __forceinline__ float interp_f32(const float* __restrict__ p,
                                            int off00, int off01, int off10, int off11,
                                            float wy, float wx, int ysingle, int xsingle)
{
    float v00 = p[off00], v01 = p[off01];
    float t0, t1;
    if (ysingle) {
        t0 = v00; t1 = v01;
    } else {
        float v10 = p[off10], v11 = p[off11];
        float wy0 = 1.0f - wy;                       // exact dyadic
        t0 = __fmaf_rn(wy, v10, __fmul_rn(wy0, v00));
        t1 = __fmaf_rn(wy, v11, __fmul_rn(wy0, v01));
    }
    if (xsingle) return t0;
    float wx0 = 1.0f - wx;
    return __fmaf_rn(wx, t1, __fmul_rn(wx0, t0));
}

// ---------------------------------------------------------------------------
// Fused: stage3 conv (fp32 chain) + bilinear gathers + ordered sum + vote.
// ---------------------------------------------------------------------------
__global__ __launch_bounds__(256)
void fuse_vote(const float* __restrict__ x3, const float* __restrict__ w3,
               const float* __restrict__ b3,
               const float* __restrict__ c0buf, const float* __restrict__ c1buf,
               const float* __restrict__ c2buf,
               float* __restrict__ out)
{
    const int n  = blockIdx.z;
    const int tx = threadIdx.x & 15, ty = threadIdx.x >> 4;
    const int X  = blockIdx.x * 16 + tx;
    const int Y  = blockIdx.y * 16 + ty;

    __shared__ float wsm[N_OVO * 64];
    __shared__ float bsm[N_OVO];
    for (int idx = threadIdx.x; idx < N_OVO * 64; idx += 256) wsm[idx] = w3[idx];
    if (threadIdx.x < N_OVO) bsm[threadIdx.x] = b3[threadIdx.x];
    __syncthreads();

    float xr[64];
    {
        const float* xp = x3 + (size_t)n * 64 * 65536 + (size_t)Y * 256 + X;
#pragma unroll
        for (int c = 0; c < 64; ++c) xr[c] = xp[(size_t)c * 65536];
    }

    // taps for S = 32, 64, 128 (half-pixel; exact dyadic weights)
    int off00[3], off01[3], off10[3], off11[3], ysing[3], xsing[3];
    float wxv[3], wyv[3];
    const int Ss[3] = {32, 64, 128};
#pragma unroll
    for (int s = 0; s < 3; ++s) {
        int   S   = Ss[s];
        float inv = (float)S * (1.0f / 256.0f);
        float fx  = ((float)X + 0.5f) * inv - 0.5f;   // exact
        float fy  = ((float)Y + 0.5f) * inv - 0.5f;
        int ix0 = (int)floorf(fx), iy0 = (int)floorf(fy);
        wxv[s] = fx - (float)ix0;  wyv[s] = fy - (float)iy0;
        xsing[s] = (ix0 < 0) || (ix0 + 1 > S - 1);
        ysing[s] = (iy0 < 0) || (iy0 + 1 > S - 1);
        int ix0c = ix0 < 0 ? 0 : ix0;
        int ix1c = (ix0 + 1 > S - 1) ? S - 1 : ix0 + 1;
        int iy0c = iy0 < 0 ? 0 : iy0;
        int iy1c = (iy0 + 1 > S - 1) ? S - 1 : iy0 + 1;
        off00[s] = iy0c * S + ix0c;  off01[s] = iy0c * S + ix1c;
        off10[s] = iy1c * S + ix0c;  off11[s] = iy1c * S + ix1c;
    }

    int votes[N_CLS];
#pragma unroll
    for (int k = 0; k < N_CLS; ++k) votes[k] = 0;

    const float* bufs[3] = {c0buf, c1buf, c2buf};
    const int    SS2[3]  = {1024, 4096, 16384};

    for (int o = 0; o < N_OVO; o += 2) {
        // two independent fp32 FMA chains for ILP; each chain strict c-ascending
        float a0 = 0.0f, a1 = 0.0f;
#pragma unroll
        for (int c = 0; c < 64; ++c) {
            a0 = __fmaf_rn(wsm[o * 64 + c],       xr[c], a0);
            a1 = __fmaf_rn(wsm[(o + 1) * 64 + c], xr[c], a1);
        }
        float L3a = __fadd_rn(a0, bsm[o]);
        float L3b = __fadd_rn(a1, bsm[o + 1]);

        float La[3], Lb[3];
#pragma unroll
        for (int s = 0; s < 3; ++s) {
            const float* pa = bufs[s] + (size_t)(n * N_OVO + o) * SS2[s];
            const float* pb = pa + SS2[s];
            La[s] = interp_f32(pa, off00[s], off01[s], off10[s], off11[s],
                               wyv[s], wxv[s], ysing[s], xsing[s]);
            Lb[s] = interp_f32(pb, off00[s], off01[s], off10[s], off11[s],
                               wyv[s], wxv[s], ysing[s], xsing[s]);
        }

        // reference order: ((L0 + L1) + L2) + L3
        float ta = __fadd_rn(__fadd_rn(__fadd_rn(La[0], La[1]), La[2]), L3a);
        float tb = __fadd_rn(__fadd_rn(__fadd_rn(Lb[0], Lb[1]), Lb[2]), L3b);

        if (ta > 0.0f) votes[PAIR_I[o]]++;     else votes[PAIR_J[o]]++;
        if (tb > 0.0f) votes[PAIR_I[o + 1]]++; else votes[PAIR_J[o + 1]]++;
    }

    float* op = out + (size_t)n * N_CLS * 65536 + (size_t)Y * 256 + X;
#pragma unroll
    for (int k = 0; k < N_CLS; ++k) op[(size_t)k * 65536] = (float)votes[k];
}

// ---------------------------------------------------------------------------
extern "C" void kernel_launch(void* const* d_in, const int* in_sizes, int n_in,
                              void* d_out, int out_size, void* d_ws, size_t ws_size,
                              hipStream_t stream)
{
    const float* stage0 = (const float*)d_in[0];
    const float* w0     = (const float*)d_in[1];
    const float* b0     = (const float*)d_in[2];
    const float* stage1 = (const float*)d_in[3];
    const float* w1     = (const float*)d_in[4];
    const float* b1     = (const float*)d_in[5];
    const float* stage2 = (const float*)d_in[6];
    const float* w2     = (const float*)d_in[7];
    const float* b2     = (const float*)d_in[8];
    const float* stage3 = (const float*)d_in[9];
    const float* w3     = (const float*)d_in[10];
    const float* b3     = (const float*)d_in[11];
    float* out = (float*)d_out;

    // fp32 workspace: c0 8*66*1024, c1 8*66*4096, c2 8*66*16384 (45.4 MB)
    float* c0 = (float*)d_ws;
    float* c1 = c0 + (size_t)540672;
    float* c2 = c1 + (size_t)2162688;

    conv1x1_f32<512, 1024><<<dim3(1024 / 64, N_BATCH), 256, 0, stream>>>(stage0, w0, b0, c0);
    conv1x1_f32<256, 4096><<<dim3(4096 / 64, N_BATCH), 256, 0, stream>>>(stage1, w1, b1, c1);
    conv1x1_f32<128, 16384><<<dim3(16384 / 64, N_BATCH), 256, 0, stream>>>(stage2, w2, b2, c2);

    fuse_vote<<<dim3(16, 16, N_BATCH), 256, 0, stream>>>(stage3, w3, b3, c0, c1, c2, out);
}

// Round 3
// 985.406 us; speedup vs baseline: 1.2339x; 1.2339x over previous
//
#include <hip/hip_runtime.h>
#include <cstdint>
#include <cstddef>

// OVOLinearSemanticExtractor (last_only=1) — exact fp32 replication (passed R2
// with absmax 0.0); this round is pure perf restructuring:
//  - convs: weights via uniform-index scalar loads (o0 from blockIdx), x in
//    VGPR chunks; no LDS at all.
//  - fuse: per-block LDS staging of all 66 bilinear source tiles; hot loop is
//    VALU + LDS only. Packed nibble vote counter.

#define N_BATCH 8
#define N_OVO   66
#define N_CLS   12

__constant__ unsigned char PAIR_I[N_OVO] = {
  0,0,0,0,0,0,0,0,0,0,0,
  1,1,1,1,1,1,1,1,1,1,
  2,2,2,2,2,2,2,2,2,
  3,3,3,3,3,3,3,3,
  4,4,4,4,4,4,4,
  5,5,5,5,5,5,
  6,6,6,6,6,
  7,7,7,7,
  8,8,8,
  9,9,
  10
};
__constant__ unsigned char PAIR_J[N_OVO] = {
  1,2,3,4,5,6,7,8,9,10,11,
  2,3,4,5,6,7,8,9,10,11,
  3,4,5,6,7,8,9,10,11,
  4,5,6,7,8,9,10,11,
  5,6,7,8,9,10,11,
  6,7,8,9,10,11,
  7,8,9,10,11,
  8,9,10,11,
  9,10,11,
  10,11,
  11
};

// ---------------------------------------------------------------------------
// Conv 1x1, fp32 exact chain (c ascending, init 0, +bias at end).
// Block = 64 threads = 64 pixels. blockIdx.y picks the o-group (uniform =>
// weight loads become s_load; v_fma takes SGPR operand). OG outputs/thread.
// ---------------------------------------------------------------------------
template<int C, int S2, int OG>
__global__ __launch_bounds__(64)
void conv1x1_f32(const float* __restrict__ x, const float* __restrict__ w,
                 const float* __restrict__ b, float* __restrict__ out)
{
    const int p  = blockIdx.x * 64 + threadIdx.x;
    const int o0 = blockIdx.y * OG;       // uniform (blockIdx) -> scalar weights
    const int n  = blockIdx.z;

    float acc[OG];
#pragma unroll
    for (int oi = 0; oi < OG; ++oi) acc[oi] = 0.0f;

    for (int c0 = 0; c0 < C; c0 += 16) {
        float xr[16];
#pragma unroll
        for (int k = 0; k < 16; ++k)
            xr[k] = x[((size_t)n * C + (c0 + k)) * S2 + p];
#pragma unroll
        for (int oi = 0; oi < OG; ++oi) {
            const float* wrow = w + (size_t)(o0 + oi) * C + c0;
#pragma unroll
            for (int k = 0; k < 16; ++k)
                acc[oi] = __fmaf_rn(wrow[k], xr[k], acc[oi]);
        }
    }

#pragma unroll
    for (int oi = 0; oi < OG; ++oi)
        out[((size_t)n * N_OVO + (o0 + oi)) * S2 + p] = __fadd_rn(acc[oi], b[o0 + oi]);
}

// ---------------------------------------------------------------------------
// Fused stage: per-block LDS staging of bilinear source tiles for all 66
// pairs, then stage3 conv (scalar weights) + LDS interp + packed vote.
// Tile widths: S=32 -> 4, S=64 -> 6, S=128 -> 10 (span+2, proven bounds).
// ---------------------------------------------------------------------------
#define WT0 4
#define WT1 6
#define WT2 10

__global__ __launch_bounds__(256)
void fuse_vote(const float* __restrict__ x3, const float* __restrict__ w3,
               const float* __restrict__ b3,
               const float* __restrict__ c0buf, const float* __restrict__ c1buf,
               const float* __restrict__ c2buf,
               float* __restrict__ out)
{
    const int n  = blockIdx.z;
    const int tx = threadIdx.x & 15, ty = threadIdx.x >> 4;
    const int X0 = blockIdx.x * 16,  Y0 = blockIdx.y * 16;
    const int X  = X0 + tx,          Y  = Y0 + ty;

    __shared__ float t0s[WT0 * WT0 * N_OVO];   // [rel][o]
    __shared__ float t1s[WT1 * WT1 * N_OVO];
    __shared__ float t2s[WT2 * WT2 * N_OVO];   // total 40,128 B

    // ---- per-thread taps (identical float math to the passing R2 kernel) ----
    int rel00[3], rel01[3], rel10[3], rel11[3], ysing[3], xsing[3];
    float wxv[3], wyv[3];
    int x0raw[3], y0raw[3];
    const int   Ss[3]  = {32, 64, 128};
    const float invs[3] = {32.0f / 256.0f, 64.0f / 256.0f, 128.0f / 256.0f};
    const int   Wt[3]  = {WT0, WT1, WT2};
#pragma unroll
    for (int s = 0; s < 3; ++s) {
        float inv = invs[s];
        int S = Ss[s];
        // block origin (uniform)
        x0raw[s] = (int)floorf(((float)X0 + 0.5f) * inv - 0.5f);
        y0raw[s] = (int)floorf(((float)Y0 + 0.5f) * inv - 0.5f);
        // this thread
        float fx = ((float)X + 0.5f) * inv - 0.5f;
        float fy = ((float)Y + 0.5f) * inv - 0.5f;
        int ix0 = (int)floorf(fx), iy0 = (int)floorf(fy);
        wxv[s] = fx - (float)ix0;  wyv[s] = fy - (float)iy0;
        xsing[s] = (ix0 < 0) || (ix0 + 1 > S - 1);
        ysing[s] = (iy0 < 0) || (iy0 + 1 > S - 1);
        int rx = ix0 - x0raw[s], ry = iy0 - y0raw[s];
        rel00[s] = ry * Wt[s] + rx;
        rel01[s] = rel00[s] + 1;
        rel10[s] = rel00[s] + Wt[s];
        rel11[s] = rel10[s] + 1;
    }

    // ---- cooperative staging (clamping baked into the tiles) ----
    {
        const float* pl = c0buf + (size_t)n * N_OVO * 1024;
        for (int idx = threadIdx.x; idx < N_OVO * WT0 * WT0; idx += 256) {
            int o = idx / (WT0 * WT0); int r = idx - o * (WT0 * WT0);
            int ry = r / WT0, rx = r - ry * WT0;
            int sy = min(max(y0raw[0] + ry, 0), 31);
            int sx = min(max(x0raw[0] + rx, 0), 31);
            t0s[r * N_OVO + o] = pl[(size_t)o * 1024 + sy * 32 + sx];
        }
    }
    {
        const float* pl = c1buf + (size_t)n * N_OVO * 4096;
        for (int idx = threadIdx.x; idx < N_OVO * WT1 * WT1; idx += 256) {
            int o = idx / (WT1 * WT1); int r = idx - o * (WT1 * WT1);
            int ry = r / WT1, rx = r - ry * WT1;
            int sy = min(max(y0raw[1] + ry, 0), 63);
            int sx = min(max(x0raw[1] + rx, 0), 63);
            t1s[r * N_OVO + o] = pl[(size_t)o * 4096 + sy * 64 + sx];
        }
    }
    {
        const float* pl = c2buf + (size_t)n * N_OVO * 16384;
        for (int idx = threadIdx.x; idx < N_OVO * WT2 * WT2; idx += 256) {
            int o = idx / (WT2 * WT2); int r = idx - o * (WT2 * WT2);
            int ry = r / WT2, rx = r - ry * WT2;
            int sy = min(max(y0raw[2] + ry, 0), 127);
            int sx = min(max(x0raw[2] + rx, 0), 127);
            t2s[r * N_OVO + o] = pl[(size_t)o * 16384 + sy * 128 + sx];
        }
    }

    // stage3 channel column (coalesced; overlaps staging latency)
    float xr[64];
    {
        const float* xp = x3 + (size_t)n * 64 * 65536 + (size_t)Y * 256 + X;
#pragma unroll
        for (int c = 0; c < 64; ++c) xr[c] = xp[(size_t)c * 65536];
    }

    __syncthreads();

    unsigned long long packed = 0;   // 12 classes x 4-bit counts (max 11)

#pragma unroll 2
    for (int o = 0; o < N_OVO; ++o) {
        // stage3 dot: strict c-ascending fp32 FMA chain, scalar weights
        float a0 = 0.0f;
        const float* wrow = w3 + (size_t)o * 64;
#pragma unroll
        for (int c = 0; c < 64; ++c)
            a0 = __fmaf_rn(wrow[c], xr[c], a0);
        float L3 = __fadd_rn(a0, b3[o]);

        float L[3];
#pragma unroll
        for (int s = 0; s < 3; ++s) {
            const float* t = (s == 0) ? t0s : (s == 1) ? t1s : t2s;
            float v00 = t[rel00[s] * N_OVO + o], v01 = t[rel01[s] * N_OVO + o];
            float v10 = t[rel10[s] * N_OVO + o], v11 = t[rel11[s] * N_OVO + o];
            float wy = wyv[s], wx = wxv[s];
            float wy0 = 1.0f - wy, wx0 = 1.0f - wx;
            float u0 = ysing[s] ? v00 : __fmaf_rn(wy, v10, __fmul_rn(wy0, v00));
            float u1 = ysing[s] ? v01 : __fmaf_rn(wy, v11, __fmul_rn(wy0, v01));
            L[s] = xsing[s] ? u0 : __fmaf_rn(wx, u1, __fmul_rn(wx0, u0));
        }

        // reference order: ((L0 + L1) + L2) + L3
        float tsum = __fadd_rn(__fadd_rn(__fadd_rn(L[0], L[1]), L[2]), L3);

        unsigned long long inc_i = 1ull << (4 * (int)PAIR_I[o]);
        unsigned long long inc_j = 1ull << (4 * (int)PAIR_J[o]);
        packed += (tsum > 0.0f) ? inc_i : inc_j;
    }

    float* op = out + (size_t)n * N_CLS * 65536 + (size_t)Y * 256 + X;
#pragma unroll
    for (int k = 0; k < N_CLS; ++k)
        op[(size_t)k * 65536] = (float)(int)((packed >> (4 * k)) & 15ull);
}

// ---------------------------------------------------------------------------
extern "C" void kernel_launch(void* const* d_in, const int* in_sizes, int n_in,
                              void* d_out, int out_size, void* d_ws, size_t ws_size,
                              hipStream_t stream)
{
    const float* stage0 = (const float*)d_in[0];
    const float* w0     = (const float*)d_in[1];
    const float* b0     = (const float*)d_in[2];
    const float* stage1 = (const float*)d_in[3];
    const float* w1     = (const float*)d_in[4];
    const float* b1     = (const float*)d_in[5];
    const float* stage2 = (const float*)d_in[6];
    const float* w2     = (const float*)d_in[7];
    const float* b2     = (const float*)d_in[8];
    const float* stage3 = (const float*)d_in[9];
    const float* w3     = (const float*)d_in[10];
    const float* b3     = (const float*)d_in[11];
    float* out = (float*)d_out;

    // fp32 workspace: c0 8*66*1024, c1 8*66*4096, c2 8*66*16384 (45.4 MB)
    float* c0 = (float*)d_ws;
    float* c1 = c0 + (size_t)540672;
    float* c2 = c1 + (size_t)2162688;

    // stage0: 1024 px, OG=11 -> grid 16x6x8;  stage1: OG=33; stage2: OG=66
    conv1x1_f32<512,  1024, 11><<<dim3(1024 / 64,  6, N_BATCH), 64, 0, stream>>>(stage0, w0, b0, c0);
    conv1x1_f32<256,  4096, 33><<<dim3(4096 / 64,  2, N_BATCH), 64, 0, stream>>>(stage1, w1, b1, c1);
    conv1x1_f32<128, 16384, 66><<<dim3(16384 / 64, 1, N_BATCH), 64, 0, stream>>>(stage2, w2, b2, c2);

    fuse_vote<<<dim3(16, 16, N_BATCH), 256, 0, stream>>>(stage3, w3, b3, c0, c1, c2, out);
}

// Round 4
// 655.706 us; speedup vs baseline: 1.8543x; 1.5028x over previous
//
#include <hip/hip_runtime.h>
#include <cstdint>
#include <cstddef>

// OVOLinearSemanticExtractor (last_only=1) — exact fp32 replication (absmax 0.0
// since R2). R4: conv occupancy fix (256-thr blocks, OG=11, og-major grid for
// L2 x-reuse) + fuse_vote VGPR fix (launch_bounds cap 128 so xr[64] stays in
// VGPRs, not AGPRs) + LDS tile padding 66->67 to kill bank conflicts.

#define N_BATCH 8
#define N_OVO   66
#define N_CLS   12
#define OV_PAD  67   // LDS tile stride: 3*rel mod 32 invertible -> conflict-free

__constant__ unsigned char PAIR_I[N_OVO] = {
  0,0,0,0,0,0,0,0,0,0,0,
  1,1,1,1,1,1,1,1,1,1,
  2,2,2,2,2,2,2,2,2,
  3,3,3,3,3,3,3,3,
  4,4,4,4,4,4,4,
  5,5,5,5,5,5,
  6,6,6,6,6,
  7,7,7,7,
  8,8,8,
  9,9,
  10
};
__constant__ unsigned char PAIR_J[N_OVO] = {
  1,2,3,4,5,6,7,8,9,10,11,
  2,3,4,5,6,7,8,9,10,11,
  3,4,5,6,7,8,9,10,11,
  4,5,6,7,8,9,10,11,
  5,6,7,8,9,10,11,
  6,7,8,9,10,11,
  7,8,9,10,11,
  8,9,10,11,
  9,10,11,
  10,11,
  11
};

// ---------------------------------------------------------------------------
// Conv 1x1, fp32 exact chain (c ascending, init 0, +bias at end).
// 256-thread blocks = 256 pixels. OG=11 outputs/thread => 88 scalar weight
// dwords per k-chunk (fits SGPR file). og-group is blockIdx.x (fastest) so all
// 6 groups over one pixel window co-run -> x re-reads hit L2.
// ---------------------------------------------------------------------------
template<int C, int S2, int OG>
__global__ __launch_bounds__(256)
void conv1x1_f32(const float* __restrict__ x, const float* __restrict__ w,
                 const float* __restrict__ b, float* __restrict__ out)
{
    const int o0 = blockIdx.x * OG;               // uniform -> scalar weights
    const int p  = blockIdx.y * 256 + threadIdx.x;
    const int n  = blockIdx.z;

    float acc[OG];
#pragma unroll
    for (int oi = 0; oi < OG; ++oi) acc[oi] = 0.0f;

    const float* xb = x + (size_t)n * C * S2 + p;
    for (int c0 = 0; c0 < C; c0 += 8) {
        float xr[8];
#pragma unroll
        for (int k = 0; k < 8; ++k)
            xr[k] = xb[(size_t)(c0 + k) * S2];
#pragma unroll
        for (int oi = 0; oi < OG; ++oi) {
            const float* wrow = w + (size_t)(o0 + oi) * C + c0;
#pragma unroll
            for (int k = 0; k < 8; ++k)
                acc[oi] = __fmaf_rn(wrow[k], xr[k], acc[oi]);
        }
    }

#pragma unroll
    for (int oi = 0; oi < OG; ++oi)
        out[((size_t)n * N_OVO + (o0 + oi)) * S2 + p] = __fadd_rn(acc[oi], b[o0 + oi]);
}

// ---------------------------------------------------------------------------
// Fused stage: LDS staging of bilinear source tiles (padded stride), stage3
// conv with scalar weights + xr[64] in VGPRs, interp + packed nibble vote.
// ---------------------------------------------------------------------------
#define WT0 4
#define WT1 6
#define WT2 10

__global__ __launch_bounds__(256, 4)   // cap 128 VGPR: xr[64] stays in VGPRs
void fuse_vote(const float* __restrict__ x3, const float* __restrict__ w3,
               const float* __restrict__ b3,
               const float* __restrict__ c0buf, const float* __restrict__ c1buf,
               const float* __restrict__ c2buf,
               float* __restrict__ out)
{
    const int n  = blockIdx.z;
    const int tx = threadIdx.x & 15, ty = threadIdx.x >> 4;
    const int X0 = blockIdx.x * 16,  Y0 = blockIdx.y * 16;
    const int X  = X0 + tx,          Y  = Y0 + ty;

    __shared__ float t0s[WT0 * WT0 * OV_PAD];
    __shared__ float t1s[WT1 * WT1 * OV_PAD];
    __shared__ float t2s[WT2 * WT2 * OV_PAD];   // ~40.7 KB total

    // ---- per-thread taps (identical float math to the passing R2/R3 kernel) ----
    int rel00[3], rel01[3], rel10[3], rel11[3], ysing[3], xsing[3];
    float wxv[3], wyv[3];
    int x0raw[3], y0raw[3];
    const int   Ss[3]   = {32, 64, 128};
    const float invs[3] = {32.0f / 256.0f, 64.0f / 256.0f, 128.0f / 256.0f};
    const int   Wt[3]   = {WT0, WT1, WT2};
#pragma unroll
    for (int s = 0; s < 3; ++s) {
        float inv = invs[s];
        int S = Ss[s];
        x0raw[s] = (int)floorf(((float)X0 + 0.5f) * inv - 0.5f);
        y0raw[s] = (int)floorf(((float)Y0 + 0.5f) * inv - 0.5f);
        float fx = ((float)X + 0.5f) * inv - 0.5f;
        float fy = ((float)Y + 0.5f) * inv - 0.5f;
        int ix0 = (int)floorf(fx), iy0 = (int)floorf(fy);
        wxv[s] = fx - (float)ix0;  wyv[s] = fy - (float)iy0;
        xsing[s] = (ix0 < 0) || (ix0 + 1 > S - 1);
        ysing[s] = (iy0 < 0) || (iy0 + 1 > S - 1);
        int rx = ix0 - x0raw[s], ry = iy0 - y0raw[s];
        rel00[s] = ry * Wt[s] + rx;
        rel01[s] = rel00[s] + 1;
        rel10[s] = rel00[s] + Wt[s];
        rel11[s] = rel10[s] + 1;
    }

    // ---- cooperative staging (clamping baked into the tiles) ----
    {
        const float* pl = c0buf + (size_t)n * N_OVO * 1024;
        for (int idx = threadIdx.x; idx < N_OVO * WT0 * WT0; idx += 256) {
            int o = idx / (WT0 * WT0); int r = idx - o * (WT0 * WT0);
            int ry = r / WT0, rx = r - ry * WT0;
            int sy = min(max(y0raw[0] + ry, 0), 31);
            int sx = min(max(x0raw[0] + rx, 0), 31);
            t0s[r * OV_PAD + o] = pl[(size_t)o * 1024 + sy * 32 + sx];
        }
    }
    {
        const float* pl = c1buf + (size_t)n * N_OVO * 4096;
        for (int idx = threadIdx.x; idx < N_OVO * WT1 * WT1; idx += 256) {
            int o = idx / (WT1 * WT1); int r = idx - o * (WT1 * WT1);
            int ry = r / WT1, rx = r - ry * WT1;
            int sy = min(max(y0raw[1] + ry, 0), 63);
            int sx = min(max(x0raw[1] + rx, 0), 63);
            t1s[r * OV_PAD + o] = pl[(size_t)o * 4096 + sy * 64 + sx];
        }
    }
    {
        const float* pl = c2buf + (size_t)n * N_OVO * 16384;
        for (int idx = threadIdx.x; idx < N_OVO * WT2 * WT2; idx += 256) {
            int o = idx / (WT2 * WT2); int r = idx - o * (WT2 * WT2);
            int ry = r / WT2, rx = r - ry * WT2;
            int sy = min(max(y0raw[2] + ry, 0), 127);
            int sx = min(max(x0raw[2] + rx, 0), 127);
            t2s[r * OV_PAD + o] = pl[(size_t)o * 16384 + sy * 128 + sx];
        }
    }

    // stage3 channel column, coalesced; keep resident in VGPRs
    float xr[64];
    {
        const float* xp = x3 + (size_t)n * 64 * 65536 + (size_t)Y * 256 + X;
#pragma unroll
        for (int c = 0; c < 64; ++c) xr[c] = xp[(size_t)c * 65536];
    }

    __syncthreads();

    unsigned long long packed = 0;   // 12 classes x 4-bit counts (max 11)

    for (int o = 0; o < N_OVO; o += 2) {
        // two independent strict c-ascending fp32 FMA chains (scalar weights)
        float a0 = 0.0f, a1 = 0.0f;
        const float* wr0 = w3 + (size_t)o * 64;
        const float* wr1 = wr0 + 64;
#pragma unroll
        for (int c = 0; c < 64; ++c) {
            a0 = __fmaf_rn(wr0[c], xr[c], a0);
            a1 = __fmaf_rn(wr1[c], xr[c], a1);
        }
        float L3a = __fadd_rn(a0, b3[o]);
        float L3b = __fadd_rn(a1, b3[o + 1]);

        float La[3], Lb[3];
#pragma unroll
        for (int s = 0; s < 3; ++s) {
            const float* t = (s == 0) ? t0s : (s == 1) ? t1s : t2s;
            float wy = wyv[s], wx = wxv[s];
            float wy0 = 1.0f - wy, wx0 = 1.0f - wx;
            {
                float v00 = t[rel00[s] * OV_PAD + o], v01 = t[rel01[s] * OV_PAD + o];
                float v10 = t[rel10[s] * OV_PAD + o], v11 = t[rel11[s] * OV_PAD + o];
                float u0 = ysing[s] ? v00 : __fmaf_rn(wy, v10, __fmul_rn(wy0, v00));
                float u1 = ysing[s] ? v01 : __fmaf_rn(wy, v11, __fmul_rn(wy0, v01));
                La[s] = xsing[s] ? u0 : __fmaf_rn(wx, u1, __fmul_rn(wx0, u0));
            }
            {
                float v00 = t[rel00[s] * OV_PAD + o + 1], v01 = t[rel01[s] * OV_PAD + o + 1];
                float v10 = t[rel10[s] * OV_PAD + o + 1], v11 = t[rel11[s] * OV_PAD + o + 1];
                float u0 = ysing[s] ? v00 : __fmaf_rn(wy, v10, __fmul_rn(wy0, v00));
                float u1 = ysing[s] ? v01 : __fmaf_rn(wy, v11, __fmul_rn(wy0, v01));
                Lb[s] = xsing[s] ? u0 : __fmaf_rn(wx, u1, __fmul_rn(wx0, u0));
            }
        }

        // reference order: ((L0 + L1) + L2) + L3
        float ta = __fadd_rn(__fadd_rn(__fadd_rn(La[0], La[1]), La[2]), L3a);
        float tb = __fadd_rn(__fadd_rn(__fadd_rn(Lb[0], Lb[1]), Lb[2]), L3b);

        packed += (ta > 0.0f) ? (1ull << (4 * (int)PAIR_I[o]))
                              : (1ull << (4 * (int)PAIR_J[o]));
        packed += (tb > 0.0f) ? (1ull << (4 * (int)PAIR_I[o + 1]))
                              : (1ull << (4 * (int)PAIR_J[o + 1]));
    }

    float* op = out + (size_t)n * N_CLS * 65536 + (size_t)Y * 256 + X;
#pragma unroll
    for (int k = 0; k < N_CLS; ++k)
        op[(size_t)k * 65536] = (float)(int)((packed >> (4 * k)) & 15ull);
}

// ---------------------------------------------------------------------------
extern "C" void kernel_launch(void* const* d_in, const int* in_sizes, int n_in,
                              void* d_out, int out_size, void* d_ws, size_t ws_size,
                              hipStream_t stream)
{
    const float* stage0 = (const float*)d_in[0];
    const float* w0     = (const float*)d_in[1];
    const float* b0     = (const float*)d_in[2];
    const float* stage1 = (const float*)d_in[3];
    const float* w1     = (const float*)d_in[4];
    const float* b1     = (const float*)d_in[5];
    const float* stage2 = (const float*)d_in[6];
    const float* w2     = (const float*)d_in[7];
    const float* b2     = (const float*)d_in[8];
    const float* stage3 = (const float*)d_in[9];
    const float* w3     = (const float*)d_in[10];
    const float* b3     = (const float*)d_in[11];
    float* out = (float*)d_out;

    // fp32 workspace: c0 8*66*1024, c1 8*66*4096, c2 8*66*16384 (45.4 MB)
    float* c0 = (float*)d_ws;
    float* c1 = c0 + (size_t)540672;
    float* c2 = c1 + (size_t)2162688;

    // grid = (og_groups, px_blocks, n); og fastest for L2 x-reuse
    conv1x1_f32<512,  1024, 11><<<dim3(6,  4, N_BATCH), 256, 0, stream>>>(stage0, w0, b0, c0);
    conv1x1_f32<256,  4096, 11><<<dim3(6, 16, N_BATCH), 256, 0, stream>>>(stage1, w1, b1, c1);
    conv1x1_f32<128, 16384, 11><<<dim3(6, 64, N_BATCH), 256, 0, stream>>>(stage2, w2, b2, c2);

    fuse_vote<<<dim3(16, 16, N_BATCH), 256, 0, stream>>>(stage3, w3, b3, c0, c1, c2, out);
}